// Round 4
// baseline (404.313 us; speedup 1.0000x reference)
//
#include <hip/hip_runtime.h>
#include <hip/hip_bf16.h>
#include <stdint.h>

// Problem constants
#define N_S   16
#define C_IN  256
#define CMID  64
#define HH    96
#define WW    96
#define HW    9216     // 96*96
#define PL2   128      // PLANES/2

// smalls[] fp32 layout (element offsets)
#define CB_OFF   0     // conv_b[64]
#define KW_OFF   64    // conv_kernel_w[25]
#define KB_OFF   96    // conv_kernel_b[25]
#define K2W_OFF  128   // conv_kernel2_w[9]
#define K2B_OFF  144   // conv_kernel2_b[9]
#define FB_OFF   160   // fuse_b[128]
#define AB_OFF   288   // adap_b[64]
#define ATB_OFF  352   // atrous_b[64]
#define SC_OFF   416   // conv_k_w, conv_k_b, conv_k2_w, conv_k2_b

typedef __attribute__((ext_vector_type(8))) short short8;   // 8 bf16 = 4 VGPRs
typedef __attribute__((ext_vector_type(4))) float floatx4;  // MFMA acc

// ---------- bf16 helpers ----------
__device__ __forceinline__ float ldbf(const uint16_t* p) {
    return __uint_as_float(((uint32_t)(*p)) << 16);
}
__device__ __forceinline__ uint16_t f2bf(float f) {
    __hip_bfloat16 h = __float2bfloat16(f);
    return *reinterpret_cast<uint16_t*>(&h);
}
__device__ __forceinline__ uint32_t pkbf(float lo, float hi) {
    return (uint32_t)f2bf(lo) | ((uint32_t)f2bf(hi) << 16);
}
__device__ __forceinline__ float bfsum2(uint32_t u) {     // sum of packed bf16 pair
    return __uint_as_float(u << 16) + __uint_as_float(u & 0xffff0000u);
}

// f_lds swizzle for k_dwfuse: distinct banks for row deltas 1 and 4/8/12
#define SWZ8(row) ((((row) ^ ((row) >> 3)) & 7) << 3)

// ---------- P0: dtype probe + weight normalization (16 blocks) ----------
__global__ __launch_bounds__(256) void k_prep(
    const uint16_t* __restrict__ xq,
    const void* conv_w, const void* conv_b, const void* ckw, const void* ckb,
    const void* ck2w, const void* ck2b, const void* kernw, const void* kernb,
    const void* kern2w, const void* kern2b, const void* fuse_w, const void* fuse_b,
    const void* adap_b, const void* atrous_b,
    int* __restrict__ flags,
    uint16_t* __restrict__ cw_bf, uint16_t* __restrict__ fw_bf,
    float* __restrict__ smalls) {
    __shared__ int cnt[2];
    int t = threadIdx.x;
    if (t < 2) cnt[t] = 0;
    __syncthreads();
    int cx = 0, cw = 0;
    const uint16_t* wq = (const uint16_t*)conv_w;
    for (int k = 0; k < 64; ++k) {
        uint16_t vx = xq[k * 256 + t];
        uint16_t vw = wq[k * 256 + t];
        if (((vx >> 7) & 0xFF) >= 0xC0) cx++;
        if (((vw >> 7) & 0xFF) >= 0xC0) cw++;
    }
    atomicAdd(&cnt[0], cx);
    atomicAdd(&cnt[1], cw);
    __syncthreads();
    bool f32 = cnt[1] > 64;
    if (blockIdx.x == 0 && t == 0) { flags[0] = cnt[0] > 64; flags[1] = f32; }

    for (int i = blockIdx.x * 256 + t; i < CMID * C_IN; i += 16 * 256)
        cw_bf[i] = f32 ? f2bf(((const float*)conv_w)[i]) : ((const uint16_t*)conv_w)[i];
    for (int i = blockIdx.x * 256 + t; i < PL2 * CMID; i += 16 * 256)
        fw_bf[i] = f32 ? f2bf(((const float*)fuse_w)[i]) : ((const uint16_t*)fuse_w)[i];
    if (blockIdx.x != 0) return;
    if (t < 64) {
        smalls[CB_OFF + t]  = f32 ? ((const float*)conv_b)[t]   : ldbf((const uint16_t*)conv_b + t);
        smalls[AB_OFF + t]  = f32 ? ((const float*)adap_b)[t]   : ldbf((const uint16_t*)adap_b + t);
        smalls[ATB_OFF + t] = f32 ? ((const float*)atrous_b)[t] : ldbf((const uint16_t*)atrous_b + t);
    }
    if (t < 128)
        smalls[FB_OFF + t] = f32 ? ((const float*)fuse_b)[t] : ldbf((const uint16_t*)fuse_b + t);
    if (t < 25) {
        smalls[KW_OFF + t] = f32 ? ((const float*)kernw)[t] : ldbf((const uint16_t*)kernw + t);
        smalls[KB_OFF + t] = f32 ? ((const float*)kernb)[t] : ldbf((const uint16_t*)kernb + t);
    }
    if (t < 9) {
        smalls[K2W_OFF + t] = f32 ? ((const float*)kern2w)[t] : ldbf((const uint16_t*)kern2w + t);
        smalls[K2B_OFF + t] = f32 ? ((const float*)kern2b)[t] : ldbf((const uint16_t*)kern2b + t);
    }
    if (t == 0) {
        smalls[SC_OFF + 0] = f32 ? ((const float*)ckw)[0]  : ldbf((const uint16_t*)ckw);
        smalls[SC_OFF + 1] = f32 ? ((const float*)ckb)[0]  : ldbf((const uint16_t*)ckb);
        smalls[SC_OFF + 2] = f32 ? ((const float*)ck2w)[0] : ldbf((const uint16_t*)ck2w);
        smalls[SC_OFF + 3] = f32 ? ((const float*)ck2b)[0] : ldbf((const uint16_t*)ck2b);
    }
}

// ---------- K1: f = relu(1x1 conv), depth-2 reg pipeline + LDS double-buffer ----------
// grid: 16*144 tiles of 64 px; block 256 (4 waves). Named uint4 staging regs
// (no scratch). MFMA(cc,bufA) overlaps CONVWRITE(cc+1,bufB): 4 barriers total.

#define ISSUE(cc, A0, A1, B0, B1) do {                                          \
    int c_ = (cc) * 64 + cp * 2;                                                \
    if (xf32) {                                                                 \
        const float* xb_ = (const float*)xv + ((size_t)n * C_IN + c_) * HW + px0;\
        A0 = *(const uint4*)xb_;        A1 = *(const uint4*)(xb_ + 4);          \
        B0 = *(const uint4*)(xb_ + HW); B1 = *(const uint4*)(xb_ + HW + 4);     \
    } else {                                                                    \
        const uint16_t* xb_ = (const uint16_t*)xv + ((size_t)n * C_IN + c_) * HW + px0;\
        A0 = *(const uint4*)xb_;        B0 = *(const uint4*)(xb_ + HW);         \
    }                                                                           \
} while (0)

#define CONVWRITE(cc, A0, A1, B0, B1, XL) do {                                  \
    int c_ = (cc) * 64 + cp * 2;                                                \
    uint32_t pk_[8]; float s0_, s1_;                                            \
    if (xf32) {                                                                 \
        float av_[8], bw_[8];                                                   \
        av_[0] = __uint_as_float(A0.x); av_[1] = __uint_as_float(A0.y);         \
        av_[2] = __uint_as_float(A0.z); av_[3] = __uint_as_float(A0.w);         \
        av_[4] = __uint_as_float(A1.x); av_[5] = __uint_as_float(A1.y);         \
        av_[6] = __uint_as_float(A1.z); av_[7] = __uint_as_float(A1.w);         \
        bw_[0] = __uint_as_float(B0.x); bw_[1] = __uint_as_float(B0.y);         \
        bw_[2] = __uint_as_float(B0.z); bw_[3] = __uint_as_float(B0.w);         \
        bw_[4] = __uint_as_float(B1.x); bw_[5] = __uint_as_float(B1.y);         \
        bw_[6] = __uint_as_float(B1.z); bw_[7] = __uint_as_float(B1.w);         \
        s0_ = ((av_[0] + av_[1]) + (av_[2] + av_[3]))                           \
            + ((av_[4] + av_[5]) + (av_[6] + av_[7]));                          \
        s1_ = ((bw_[0] + bw_[1]) + (bw_[2] + bw_[3]))                           \
            + ((bw_[4] + bw_[5]) + (bw_[6] + bw_[7]));                          \
        _Pragma("unroll")                                                       \
        for (int j = 0; j < 8; ++j) pk_[j] = pkbf(av_[j], bw_[j]);              \
    } else {                                                                    \
        s0_ = (bfsum2(A0.x) + bfsum2(A0.y)) + (bfsum2(A0.z) + bfsum2(A0.w));    \
        s1_ = (bfsum2(B0.x) + bfsum2(B0.y)) + (bfsum2(B0.z) + bfsum2(B0.w));    \
        pk_[0] = (A0.x & 0xffffu) | (B0.x << 16);                               \
        pk_[1] = (A0.x >> 16)     | (B0.x & 0xffff0000u);                       \
        pk_[2] = (A0.y & 0xffffu) | (B0.y << 16);                               \
        pk_[3] = (A0.y >> 16)     | (B0.y & 0xffff0000u);                       \
        pk_[4] = (A0.z & 0xffffu) | (B0.z << 16);                               \
        pk_[5] = (A0.z >> 16)     | (B0.z & 0xffff0000u);                       \
        pk_[6] = (A0.w & 0xffffu) | (B0.w << 16);                               \
        pk_[7] = (A0.w >> 16)     | (B0.w & 0xffff0000u);                       \
    }                                                                           \
    int swz_ = pxg << 2;                                                        \
    _Pragma("unroll")                                                           \
    for (int j = 0; j < 8; ++j)                                                 \
        (XL)[(pxg * 8 + j) * 36 + (cp ^ swz_)] = pk_[j];                        \
    s0_ += __shfl_xor(s0_, 4, 8); s0_ += __shfl_xor(s0_, 2, 8);                 \
    s0_ += __shfl_xor(s0_, 1, 8);                                               \
    s1_ += __shfl_xor(s1_, 4, 8); s1_ += __shfl_xor(s1_, 2, 8);                 \
    s1_ += __shfl_xor(s1_, 1, 8);                                               \
    if ((t & 7) == 0) *(float2*)(pbase + c_) = make_float2(s0_, s1_);           \
} while (0)

#define MFMA_PH(cc, XL) do {                                                    \
    _Pragma("unroll")                                                           \
    for (int ks = 0; ks < 2; ++ks) {                                            \
        int kw_ = (cc) * 64 + ks * 32 + quad * 8;                               \
        const uint16_t* wp_ = cw_bf + kw_;                                      \
        short8 a0 = *(const short8*)(wp_ + (l16)      * 256);                   \
        short8 a1 = *(const short8*)(wp_ + (16 + l16) * 256);                   \
        short8 a2 = *(const short8*)(wp_ + (32 + l16) * 256);                   \
        short8 a3 = *(const short8*)(wp_ + (48 + l16) * 256);                   \
        int kdw_ = (ks * 16 + quad * 4) ^ ((pxw >> 3) << 2);                    \
        short8 bv = *(const short8*)((XL) + (size_t)pxw * 36 + kdw_);           \
        acc[0] = __builtin_amdgcn_mfma_f32_16x16x32_bf16(a0, bv, acc[0], 0, 0, 0);\
        acc[1] = __builtin_amdgcn_mfma_f32_16x16x32_bf16(a1, bv, acc[1], 0, 0, 0);\
        acc[2] = __builtin_amdgcn_mfma_f32_16x16x32_bf16(a2, bv, acc[2], 0, 0, 0);\
        acc[3] = __builtin_amdgcn_mfma_f32_16x16x32_bf16(a3, bv, acc[3], 0, 0, 0);\
    }                                                                           \
} while (0)

__global__ __launch_bounds__(256) void k_conv1x1(
    const void* __restrict__ xv, const int* __restrict__ flags,
    const uint16_t* __restrict__ cw_bf, const float* __restrict__ smalls,
    uint16_t* __restrict__ fout, float* __restrict__ partials) {
    __shared__ uint16_t x_lds[2 * 64 * 72];   // two 9216 B buffers
    int t = threadIdx.x;
    int b = blockIdx.x;
    int n = b / 144, blk = b % 144;
    int pxb = blk * 64;
    bool xf32 = flags[0] != 0;

    int lane = t & 63, wid = t >> 6;
    int l16 = lane & 15, quad = lane >> 4;
    int pxw = wid * 16 + l16;                 // this wave's pixel (B col)
    uint32_t* xb0 = (uint32_t*)x_lds;         // buf0, [px] stride 36 dwords
    uint32_t* xb1 = xb0 + 2304;               // buf1

    // staging task: one (c-pair, 8-px group) per thread
    int pxg = t & 7, cp = t >> 3;             // pxg 0..7, cp 0..31
    int px0 = pxb + pxg * 8;

    floatx4 acc[4];
#pragma unroll
    for (int i = 0; i < 4; ++i) acc[i] = (floatx4){0.f, 0.f, 0.f, 0.f};

    float* pbase = partials + (size_t)(n * 144 + blk) * 256;

    uint4 pA0, pA1, pB0, pB1;                 // ping set
    uint4 qA0, qA1, qB0, qB1;                 // pong set

    ISSUE(0, pA0, pA1, pB0, pB1);
    CONVWRITE(0, pA0, pA1, pB0, pB1, xb0);
    ISSUE(1, qA0, qA1, qB0, qB1);
    __syncthreads();
    MFMA_PH(0, xb0);
    CONVWRITE(1, qA0, qA1, qB0, qB1, xb1);
    ISSUE(2, pA0, pA1, pB0, pB1);
    __syncthreads();
    MFMA_PH(1, xb1);
    CONVWRITE(2, pA0, pA1, pB0, pB1, xb0);
    ISSUE(3, qA0, qA1, qB0, qB1);
    __syncthreads();
    MFMA_PH(2, xb0);
    CONVWRITE(3, qA0, qA1, qB0, qB1, xb1);
    __syncthreads();
    MFMA_PH(3, xb1);

    // epilogue: D[col=px=l16][row=o=quad*4+reg]; bias+relu+bf16 -> buf0 [px][o]
    // (buf0's last readers were MFMA_PH(2), all pre-barrier; buf1 still read by
    //  other waves' MFMA_PH(3) — disjoint.)
#pragma unroll
    for (int mt = 0; mt < 4; ++mt) {
        int o = mt * 16 + quad * 4;
        float b0 = smalls[CB_OFF + o],     b1 = smalls[CB_OFF + o + 1];
        float b2 = smalls[CB_OFF + o + 2], b3 = smalls[CB_OFF + o + 3];
        float v0 = fmaxf(acc[mt][0] + b0, 0.f);
        float v1 = fmaxf(acc[mt][1] + b1, 0.f);
        float v2 = fmaxf(acc[mt][2] + b2, 0.f);
        float v3 = fmaxf(acc[mt][3] + b3, 0.f);
        *(uint2*)(x_lds + pxw * 72 + o) = make_uint2(pkbf(v0, v1), pkbf(v2, v3));
    }
    __syncthreads();
    // coalesced copy-out: f[n][pxb+pxl][o], 2 uint4 per thread
#pragma unroll
    for (int k = 0; k < 2; ++k) {
        int task = k * 256 + t;
        int o8 = (task & 7) * 8, pxl = task >> 3;
        *(uint4*)(fout + ((size_t)n * HW + pxb + pxl) * 64 + o8) =
            *(const uint4*)(x_lds + pxl * 72 + o8);
    }
}

// ---------- K2: reduce partials -> g -> dynamic depthwise weights ----------
__global__ __launch_bounds__(256) void k_weights2(
    const float* __restrict__ partials, const uint16_t* __restrict__ cw_bf,
    const float* __restrict__ smalls,
    float* __restrict__ w_dyn, float* __restrict__ w_atr) {
    __shared__ float s_sums[256];
    __shared__ float s_dot[256];
    int n = blockIdx.x, t = threadIdx.x;
    const float* pp = partials + (size_t)n * 144 * 256 + t;
    float s = 0.f;
#pragma unroll 8
    for (int k = 0; k < 144; ++k) s += pp[k * 256];
    s_sums[t] = s * (1.0f / (float)HW);
    __syncthreads();
    int cm = t & 63, seg = t >> 6;
    const uint16_t* wr = cw_bf + cm * 256 + seg * 64;
    const float* sr = s_sums + seg * 64;
    float acc = 0.f;
#pragma unroll 8
    for (int c = 0; c < 64; ++c) acc = fmaf(ldbf(wr + c), sr[c], acc);
    s_dot[t] = acc;
    __syncthreads();
    if (t < 64) {
        float a = s_dot[t] + s_dot[t + 64] + s_dot[t + 128] + s_dot[t + 192]
                + smalls[CB_OFF + t];
        float gv = fmaxf(a, 0.f);
        float ckw = smalls[SC_OFF + 0], ckb = smalls[SC_OFF + 1];
        float ck2w = smalls[SC_OFF + 2], ck2b = smalls[SC_OFF + 3];
        float* o1 = w_dyn + (size_t)(n * CMID + t) * 25;
#pragma unroll
        for (int k = 0; k < 25; ++k)
            o1[k] = fmaf(ckw, fmaf(gv, smalls[KW_OFF + k], smalls[KB_OFF + k]), ckb);
        float* o2 = w_atr + (size_t)(n * CMID + t) * 9;
#pragma unroll
        for (int k = 0; k < 9; ++k)
            o2[k] = fmaf(ck2w, fmaf(gv, smalls[K2W_OFF + k], smalls[K2B_OFF + k]), ck2b);
    }
}

// ---------- K3: dynamic depthwise (5x5 + atrous 3x3) + MFMA fuse GEMM ----------
// Row-streamed depthwise (8-reg row buffer instead of 64-reg patch) + LDS union:
// d5/dA alias the f halo buffer after all reads complete. LDS 20480 B,
// __launch_bounds__(256,5) -> 5 blocks/CU (20 waves, 62.5%).
__global__ __launch_bounds__(256, 5) void k_dwfuse(
    const uint16_t* __restrict__ f,
    const float* __restrict__ w_dyn, const float* __restrict__ w_atr,
    const uint16_t* __restrict__ fw_bf, const float* __restrict__ smalls,
    float* __restrict__ out) {
    __shared__ uint16_t u_lds[160 * 64];      // 20480 B: f halo, then d5|dA union
    uint16_t* d5_lds = u_lds;                 // [px 4x16][c] pad 72: 9216 B
    uint16_t* dA_lds = u_lds + 64 * 72;       // 9216 B (total 18432 <= 20480)

    int t = threadIdx.x;
    int orig = blockIdx.x;
    int b = (orig & 7) * 288 + (orig >> 3);   // XCD swizzle (2304 % 8 == 0, bijective)
    int n = b / 144, tile = b % 144;
    int y0 = (tile / 6) * 4, x0 = (tile % 6) * 16;

    // prefetch per-channel dynamic weights early
    int c = t >> 2, q = t & 3;
    int qx = q << 2;
    float w5[25], w9[9];
    {
        const float* wp = w_dyn + (size_t)(n * CMID + c) * 25;
#pragma unroll
        for (int k = 0; k < 25; ++k) w5[k] = wp[k];
        const float* wa = w_atr + (size_t)(n * CMID + c) * 9;
#pragma unroll
        for (int k = 0; k < 9; ++k) w9[k] = wa[k];
    }

    // stage f halo 8 rows x 20 cols x 64c (zero-padded); 1280 uint4 tasks
    const uint16_t* fbase = f + (size_t)n * HW * 64;
#pragma unroll
    for (int k = 0; k < 5; ++k) {
        int task = k * 256 + t;
        int row = task >> 3, c8 = (task & 7) * 8;
        int hy = row / 20, hx = row - hy * 20;
        int y = y0 - 2 + hy, xg = x0 - 2 + hx;
        uint4 v = make_uint4(0u, 0u, 0u, 0u);
        if (y >= 0 && y < HH && xg >= 0 && xg < WW)
            v = *(const uint4*)(fbase + ((size_t)y * WW + xg) * 64 + c8);
        *(uint4*)(u_lds + row * 64 + (c8 ^ SWZ8(row))) = v;
    }
    __syncthreads();

    // ---- row-streamed depthwise: 1 channel x 4x4 outputs per thread ----
    float b5v = smalls[AB_OFF + c], bAv = smalls[ATB_OFF + c];
    float a5[4][4], aA[4][4];
#pragma unroll
    for (int i = 0; i < 4; ++i)
#pragma unroll
        for (int j = 0; j < 4; ++j) { a5[i][j] = b5v; aA[i][j] = bAv; }

#pragma unroll
    for (int r = 0; r < 8; ++r) {
        float row[8];
#pragma unroll
        for (int cl = 0; cl < 8; ++cl) {
            int rw = r * 20 + qx + cl;
            row[cl] = ldbf(u_lds + rw * 64 + (c ^ SWZ8(rw)));
        }
#pragma unroll
        for (int oy = 0; oy < 4; ++oy) {
            int d = r - oy;
            if (d >= 0 && d <= 4) {
#pragma unroll
                for (int j = 0; j < 5; ++j) {
                    float wv = w5[d * 5 + j];
#pragma unroll
                    for (int ox = 0; ox < 4; ++ox)
                        a5[oy][ox] = fmaf(wv, row[ox + j], a5[oy][ox]);
                }
            }
            if (d >= 0 && d <= 4 && (d & 1) == 0) {
                int i2 = d >> 1;
#pragma unroll
                for (int j = 0; j < 3; ++j) {
                    float wv = w9[i2 * 3 + j];
#pragma unroll
                    for (int ox = 0; ox < 4; ++ox)
                        aA[oy][ox] = fmaf(wv, row[ox + 2 * j], aA[oy][ox]);
                }
            }
        }
    }
    __syncthreads();                          // all f reads done; union now writable

#pragma unroll
    for (int oy = 0; oy < 4; ++oy)
#pragma unroll
        for (int ox = 0; ox < 4; ox += 2) {
            int pxo = oy * 16 + qx + ox;
            uint32_t p5 = pkbf(a5[oy][ox], a5[oy][ox + 1]);
            uint32_t pA = pkbf(aA[oy][ox], aA[oy][ox + 1]);
            d5_lds[pxo * 72 + c]       = (uint16_t)p5;
            d5_lds[(pxo + 1) * 72 + c] = (uint16_t)(p5 >> 16);
            dA_lds[pxo * 72 + c]       = (uint16_t)pA;
            dA_lds[(pxo + 1) * 72 + c] = (uint16_t)(pA >> 16);
        }
    __syncthreads();

    // ---- fuse GEMM: A = d[px][c] (LDS), B = fw^T (global/L2) ----
    {
        int lane = t & 63, wid = t >> 6;
        int l16 = lane & 15, quad = lane >> 4;
        const uint16_t* dl = (wid >= 2) ? dA_lds : d5_lds;
        int oh = (wid & 1) * 64;
        int obr = (wid >= 2) ? 128 : 0;

        floatx4 acc[4][4];                    // [mt=px group][nt=o group]
#pragma unroll
        for (int i = 0; i < 4; ++i)
#pragma unroll
            for (int j = 0; j < 4; ++j) acc[i][j] = (floatx4){0.f, 0.f, 0.f, 0.f};

#pragma unroll
        for (int ks = 0; ks < 2; ++ks) {
            int kk = ks * 32 + quad * 8;
            short8 a0 = *(const short8*)(dl + (l16)      * 72 + kk);
            short8 a1 = *(const short8*)(dl + (16 + l16) * 72 + kk);
            short8 a2 = *(const short8*)(dl + (32 + l16) * 72 + kk);
            short8 a3 = *(const short8*)(dl + (48 + l16) * 72 + kk);
#pragma unroll
            for (int nt = 0; nt < 4; ++nt) {
                short8 bv = *(const short8*)(fw_bf + (size_t)(oh + nt * 16 + l16) * 64 + kk);
                acc[0][nt] = __builtin_amdgcn_mfma_f32_16x16x32_bf16(a0, bv, acc[0][nt], 0, 0, 0);
                acc[1][nt] = __builtin_amdgcn_mfma_f32_16x16x32_bf16(a1, bv, acc[1][nt], 0, 0, 0);
                acc[2][nt] = __builtin_amdgcn_mfma_f32_16x16x32_bf16(a2, bv, acc[2][nt], 0, 0, 0);
                acc[3][nt] = __builtin_amdgcn_mfma_f32_16x16x32_bf16(a3, bv, acc[3][nt], 0, 0, 0);
            }
        }
        // store: px = mt*16 + quad*4 + reg -> y = y0+mt, x = x0 + quad*4 + reg
#pragma unroll
        for (int nt = 0; nt < 4; ++nt) {
            int o = oh + nt * 16 + l16;
            float bias = smalls[FB_OFF + o];
            float* obp = out + ((size_t)(n * 256 + obr + o)) * HW + x0 + quad * 4;
#pragma unroll
            for (int mt = 0; mt < 4; ++mt) {
                float4 v;
                v.x = acc[mt][nt][0] + bias;
                v.y = acc[mt][nt][1] + bias;
                v.z = acc[mt][nt][2] + bias;
                v.w = acc[mt][nt][3] + bias;
                *(float4*)(obp + (size_t)(y0 + mt) * WW) = v;
            }
        }
    }
}

extern "C" void kernel_launch(void* const* d_in, const int* in_sizes, int n_in,
                              void* d_out, int out_size, void* d_ws, size_t ws_size,
                              hipStream_t stream) {
    float* out = (float*)d_out;                              // fp32 output

    char* ws = (char*)d_ws;
    int*      flags = (int*)ws;                              // 256 B
    uint16_t* cw_bf = (uint16_t*)(ws + 256);                 // 32768 B [o][c]
    uint16_t* fw_bf = (uint16_t*)(ws + 33024);               // 16384 B [o][c]
    float*    smalls = (float*)(ws + 49408);                 // 2048 B
    float*    partials = (float*)(ws + 65536);               // 2359296 B [n][144][256]
    float*    w_dyn = (float*)(ws + 2424832);                // 102400 B
    float*    w_atr = (float*)(ws + 2527232);                // 36864 B
    uint16_t* f     = (uint16_t*)(ws + 2564096);             // 18.9 MB [n][px][c] bf16

    k_prep<<<dim3(16), dim3(256), 0, stream>>>(
        (const uint16_t*)d_in[0],
        d_in[1], d_in[2], d_in[3], d_in[4], d_in[5], d_in[6], d_in[7], d_in[8],
        d_in[9], d_in[10], d_in[11], d_in[12], d_in[13], d_in[14],
        flags, cw_bf, fw_bf, smalls);
    k_conv1x1<<<dim3(N_S * 144), dim3(256), 0, stream>>>(
        d_in[0], flags, cw_bf, smalls, f, partials);
    k_weights2<<<dim3(N_S), dim3(256), 0, stream>>>(
        partials, cw_bf, smalls, w_dyn, w_atr);
    k_dwfuse<<<dim3(N_S * 144), dim3(256), 0, stream>>>(
        f, w_dyn, w_atr, fw_bf, smalls, out);
}

// Round 5
// 363.025 us; speedup vs baseline: 1.1137x; 1.1137x over previous
//
#include <hip/hip_runtime.h>
#include <hip/hip_bf16.h>
#include <stdint.h>

// Problem constants
#define N_S   16
#define C_IN  256
#define CMID  64
#define HH    96
#define WW    96
#define HW    9216     // 96*96
#define PL2   128      // PLANES/2

// smalls[] fp32 layout (element offsets)
#define CB_OFF   0     // conv_b[64]
#define KW_OFF   64    // conv_kernel_w[25]
#define KB_OFF   96    // conv_kernel_b[25]
#define K2W_OFF  128   // conv_kernel2_w[9]
#define K2B_OFF  144   // conv_kernel2_b[9]
#define FB_OFF   160   // fuse_b[128]
#define AB_OFF   288   // adap_b[64]
#define ATB_OFF  352   // atrous_b[64]
#define SC_OFF   416   // conv_k_w, conv_k_b, conv_k2_w, conv_k2_b

typedef __attribute__((ext_vector_type(8))) short short8;   // 8 bf16 = 4 VGPRs
typedef __attribute__((ext_vector_type(4))) float floatx4;  // MFMA acc

// ---------- bf16 helpers ----------
__device__ __forceinline__ float ldbf(const uint16_t* p) {
    return __uint_as_float(((uint32_t)(*p)) << 16);
}
__device__ __forceinline__ uint16_t f2bf(float f) {
    __hip_bfloat16 h = __float2bfloat16(f);
    return *reinterpret_cast<uint16_t*>(&h);
}
__device__ __forceinline__ uint32_t pkbf(float lo, float hi) {
    return (uint32_t)f2bf(lo) | ((uint32_t)f2bf(hi) << 16);
}
__device__ __forceinline__ float bfsum2(uint32_t u) {     // sum of packed bf16 pair
    return __uint_as_float(u << 16) + __uint_as_float(u & 0xffff0000u);
}

// f_lds swizzle for k_dwfuse: distinct banks for row deltas 1 and 4/8/12
#define SWZ8(row) ((((row) ^ ((row) >> 3)) & 7) << 3)

// ---------- P0: dtype probe + weight normalization (16 blocks) ----------
__global__ __launch_bounds__(256) void k_prep(
    const uint16_t* __restrict__ xq,
    const void* conv_w, const void* conv_b, const void* ckw, const void* ckb,
    const void* ck2w, const void* ck2b, const void* kernw, const void* kernb,
    const void* kern2w, const void* kern2b, const void* fuse_w, const void* fuse_b,
    const void* adap_b, const void* atrous_b,
    int* __restrict__ flags,
    uint16_t* __restrict__ cw_bf, uint16_t* __restrict__ fw_bf,
    float* __restrict__ smalls) {
    __shared__ int cnt[2];
    int t = threadIdx.x;
    if (t < 2) cnt[t] = 0;
    __syncthreads();
    int cx = 0, cw = 0;
    const uint16_t* wq = (const uint16_t*)conv_w;
    for (int k = 0; k < 64; ++k) {
        uint16_t vx = xq[k * 256 + t];
        uint16_t vw = wq[k * 256 + t];
        if (((vx >> 7) & 0xFF) >= 0xC0) cx++;
        if (((vw >> 7) & 0xFF) >= 0xC0) cw++;
    }
    atomicAdd(&cnt[0], cx);
    atomicAdd(&cnt[1], cw);
    __syncthreads();
    bool f32 = cnt[1] > 64;
    if (blockIdx.x == 0 && t == 0) { flags[0] = cnt[0] > 64; flags[1] = f32; }

    for (int i = blockIdx.x * 256 + t; i < CMID * C_IN; i += 16 * 256)
        cw_bf[i] = f32 ? f2bf(((const float*)conv_w)[i]) : ((const uint16_t*)conv_w)[i];
    for (int i = blockIdx.x * 256 + t; i < PL2 * CMID; i += 16 * 256)
        fw_bf[i] = f32 ? f2bf(((const float*)fuse_w)[i]) : ((const uint16_t*)fuse_w)[i];
    if (blockIdx.x != 0) return;
    if (t < 64) {
        smalls[CB_OFF + t]  = f32 ? ((const float*)conv_b)[t]   : ldbf((const uint16_t*)conv_b + t);
        smalls[AB_OFF + t]  = f32 ? ((const float*)adap_b)[t]   : ldbf((const uint16_t*)adap_b + t);
        smalls[ATB_OFF + t] = f32 ? ((const float*)atrous_b)[t] : ldbf((const uint16_t*)atrous_b + t);
    }
    if (t < 128)
        smalls[FB_OFF + t] = f32 ? ((const float*)fuse_b)[t] : ldbf((const uint16_t*)fuse_b + t);
    if (t < 25) {
        smalls[KW_OFF + t] = f32 ? ((const float*)kernw)[t] : ldbf((const uint16_t*)kernw + t);
        smalls[KB_OFF + t] = f32 ? ((const float*)kernb)[t] : ldbf((const uint16_t*)kernb + t);
    }
    if (t < 9) {
        smalls[K2W_OFF + t] = f32 ? ((const float*)kern2w)[t] : ldbf((const uint16_t*)kern2w + t);
        smalls[K2B_OFF + t] = f32 ? ((const float*)kern2b)[t] : ldbf((const uint16_t*)kern2b + t);
    }
    if (t == 0) {
        smalls[SC_OFF + 0] = f32 ? ((const float*)ckw)[0]  : ldbf((const uint16_t*)ckw);
        smalls[SC_OFF + 1] = f32 ? ((const float*)ckb)[0]  : ldbf((const uint16_t*)ckb);
        smalls[SC_OFF + 2] = f32 ? ((const float*)ck2w)[0] : ldbf((const uint16_t*)ck2w);
        smalls[SC_OFF + 3] = f32 ? ((const float*)ck2b)[0] : ldbf((const uint16_t*)ck2b);
    }
}

// ---------- K1: f = relu(1x1 conv), depth-2 reg pipeline + LDS double-buffer ----------
// grid: 16*144 tiles of 64 px; block 256 (4 waves). Named uint4 staging regs
// (no scratch). MFMA(cc,bufA) overlaps CONVWRITE(cc+1,bufB): 4 barriers total.

#define ISSUE(cc, A0, A1, B0, B1) do {                                          \
    int c_ = (cc) * 64 + cp * 2;                                                \
    if (xf32) {                                                                 \
        const float* xb_ = (const float*)xv + ((size_t)n * C_IN + c_) * HW + px0;\
        A0 = *(const uint4*)xb_;        A1 = *(const uint4*)(xb_ + 4);          \
        B0 = *(const uint4*)(xb_ + HW); B1 = *(const uint4*)(xb_ + HW + 4);     \
    } else {                                                                    \
        const uint16_t* xb_ = (const uint16_t*)xv + ((size_t)n * C_IN + c_) * HW + px0;\
        A0 = *(const uint4*)xb_;        B0 = *(const uint4*)(xb_ + HW);         \
    }                                                                           \
} while (0)

#define CONVWRITE(cc, A0, A1, B0, B1, XL) do {                                  \
    int c_ = (cc) * 64 + cp * 2;                                                \
    uint32_t pk_[8]; float s0_, s1_;                                            \
    if (xf32) {                                                                 \
        float av_[8], bw_[8];                                                   \
        av_[0] = __uint_as_float(A0.x); av_[1] = __uint_as_float(A0.y);         \
        av_[2] = __uint_as_float(A0.z); av_[3] = __uint_as_float(A0.w);         \
        av_[4] = __uint_as_float(A1.x); av_[5] = __uint_as_float(A1.y);         \
        av_[6] = __uint_as_float(A1.z); av_[7] = __uint_as_float(A1.w);         \
        bw_[0] = __uint_as_float(B0.x); bw_[1] = __uint_as_float(B0.y);         \
        bw_[2] = __uint_as_float(B0.z); bw_[3] = __uint_as_float(B0.w);         \
        bw_[4] = __uint_as_float(B1.x); bw_[5] = __uint_as_float(B1.y);         \
        bw_[6] = __uint_as_float(B1.z); bw_[7] = __uint_as_float(B1.w);         \
        s0_ = ((av_[0] + av_[1]) + (av_[2] + av_[3]))                           \
            + ((av_[4] + av_[5]) + (av_[6] + av_[7]));                          \
        s1_ = ((bw_[0] + bw_[1]) + (bw_[2] + bw_[3]))                           \
            + ((bw_[4] + bw_[5]) + (bw_[6] + bw_[7]));                          \
        _Pragma("unroll")                                                       \
        for (int j = 0; j < 8; ++j) pk_[j] = pkbf(av_[j], bw_[j]);              \
    } else {                                                                    \
        s0_ = (bfsum2(A0.x) + bfsum2(A0.y)) + (bfsum2(A0.z) + bfsum2(A0.w));    \
        s1_ = (bfsum2(B0.x) + bfsum2(B0.y)) + (bfsum2(B0.z) + bfsum2(B0.w));    \
        pk_[0] = (A0.x & 0xffffu) | (B0.x << 16);                               \
        pk_[1] = (A0.x >> 16)     | (B0.x & 0xffff0000u);                       \
        pk_[2] = (A0.y & 0xffffu) | (B0.y << 16);                               \
        pk_[3] = (A0.y >> 16)     | (B0.y & 0xffff0000u);                       \
        pk_[4] = (A0.z & 0xffffu) | (B0.z << 16);                               \
        pk_[5] = (A0.z >> 16)     | (B0.z & 0xffff0000u);                       \
        pk_[6] = (A0.w & 0xffffu) | (B0.w << 16);                               \
        pk_[7] = (A0.w >> 16)     | (B0.w & 0xffff0000u);                       \
    }                                                                           \
    int swz_ = pxg << 2;                                                        \
    _Pragma("unroll")                                                           \
    for (int j = 0; j < 8; ++j)                                                 \
        (XL)[(pxg * 8 + j) * 36 + (cp ^ swz_)] = pk_[j];                        \
    s0_ += __shfl_xor(s0_, 4, 8); s0_ += __shfl_xor(s0_, 2, 8);                 \
    s0_ += __shfl_xor(s0_, 1, 8);                                               \
    s1_ += __shfl_xor(s1_, 4, 8); s1_ += __shfl_xor(s1_, 2, 8);                 \
    s1_ += __shfl_xor(s1_, 1, 8);                                               \
    if ((t & 7) == 0) *(float2*)(pbase + c_) = make_float2(s0_, s1_);           \
} while (0)

#define MFMA_PH(cc, XL) do {                                                    \
    _Pragma("unroll")                                                           \
    for (int ks = 0; ks < 2; ++ks) {                                            \
        int kw_ = (cc) * 64 + ks * 32 + quad * 8;                               \
        const uint16_t* wp_ = cw_bf + kw_;                                      \
        short8 a0 = *(const short8*)(wp_ + (l16)      * 256);                   \
        short8 a1 = *(const short8*)(wp_ + (16 + l16) * 256);                   \
        short8 a2 = *(const short8*)(wp_ + (32 + l16) * 256);                   \
        short8 a3 = *(const short8*)(wp_ + (48 + l16) * 256);                   \
        int kdw_ = (ks * 16 + quad * 4) ^ ((pxw >> 3) << 2);                    \
        short8 bv = *(const short8*)((XL) + (size_t)pxw * 36 + kdw_);           \
        acc[0] = __builtin_amdgcn_mfma_f32_16x16x32_bf16(a0, bv, acc[0], 0, 0, 0);\
        acc[1] = __builtin_amdgcn_mfma_f32_16x16x32_bf16(a1, bv, acc[1], 0, 0, 0);\
        acc[2] = __builtin_amdgcn_mfma_f32_16x16x32_bf16(a2, bv, acc[2], 0, 0, 0);\
        acc[3] = __builtin_amdgcn_mfma_f32_16x16x32_bf16(a3, bv, acc[3], 0, 0, 0);\
    }                                                                           \
} while (0)

__global__ __launch_bounds__(256) void k_conv1x1(
    const void* __restrict__ xv, const int* __restrict__ flags,
    const uint16_t* __restrict__ cw_bf, const float* __restrict__ smalls,
    uint16_t* __restrict__ fout, float* __restrict__ partials) {
    __shared__ uint16_t x_lds[2 * 64 * 72];   // two 9216 B buffers
    int t = threadIdx.x;
    int b = blockIdx.x;
    int n = b / 144, blk = b % 144;
    int pxb = blk * 64;
    bool xf32 = flags[0] != 0;

    int lane = t & 63, wid = t >> 6;
    int l16 = lane & 15, quad = lane >> 4;
    int pxw = wid * 16 + l16;                 // this wave's pixel (B col)
    uint32_t* xb0 = (uint32_t*)x_lds;         // buf0, [px] stride 36 dwords
    uint32_t* xb1 = xb0 + 2304;               // buf1

    // staging task: one (c-pair, 8-px group) per thread
    int pxg = t & 7, cp = t >> 3;             // pxg 0..7, cp 0..31
    int px0 = pxb + pxg * 8;

    floatx4 acc[4];
#pragma unroll
    for (int i = 0; i < 4; ++i) acc[i] = (floatx4){0.f, 0.f, 0.f, 0.f};

    float* pbase = partials + (size_t)(n * 144 + blk) * 256;

    uint4 pA0, pA1, pB0, pB1;                 // ping set
    uint4 qA0, qA1, qB0, qB1;                 // pong set

    ISSUE(0, pA0, pA1, pB0, pB1);
    CONVWRITE(0, pA0, pA1, pB0, pB1, xb0);
    ISSUE(1, qA0, qA1, qB0, qB1);
    __syncthreads();
    MFMA_PH(0, xb0);
    CONVWRITE(1, qA0, qA1, qB0, qB1, xb1);
    ISSUE(2, pA0, pA1, pB0, pB1);
    __syncthreads();
    MFMA_PH(1, xb1);
    CONVWRITE(2, pA0, pA1, pB0, pB1, xb0);
    ISSUE(3, qA0, qA1, qB0, qB1);
    __syncthreads();
    MFMA_PH(2, xb0);
    CONVWRITE(3, qA0, qA1, qB0, qB1, xb1);
    __syncthreads();
    MFMA_PH(3, xb1);

    // epilogue: D[col=px=l16][row=o=quad*4+reg]; bias+relu+bf16 -> buf0 [px][o]
#pragma unroll
    for (int mt = 0; mt < 4; ++mt) {
        int o = mt * 16 + quad * 4;
        float b0 = smalls[CB_OFF + o],     b1 = smalls[CB_OFF + o + 1];
        float b2 = smalls[CB_OFF + o + 2], b3 = smalls[CB_OFF + o + 3];
        float v0 = fmaxf(acc[mt][0] + b0, 0.f);
        float v1 = fmaxf(acc[mt][1] + b1, 0.f);
        float v2 = fmaxf(acc[mt][2] + b2, 0.f);
        float v3 = fmaxf(acc[mt][3] + b3, 0.f);
        *(uint2*)(x_lds + pxw * 72 + o) = make_uint2(pkbf(v0, v1), pkbf(v2, v3));
    }
    __syncthreads();
    // coalesced copy-out: f[n][pxb+pxl][o], 2 uint4 per thread
#pragma unroll
    for (int k = 0; k < 2; ++k) {
        int task = k * 256 + t;
        int o8 = (task & 7) * 8, pxl = task >> 3;
        *(uint4*)(fout + ((size_t)n * HW + pxb + pxl) * 64 + o8) =
            *(const uint4*)(x_lds + pxl * 72 + o8);
    }
}

// ---------- K2: reduce partials -> g -> dynamic depthwise weights ----------
__global__ __launch_bounds__(256) void k_weights2(
    const float* __restrict__ partials, const uint16_t* __restrict__ cw_bf,
    const float* __restrict__ smalls,
    float* __restrict__ w_dyn, float* __restrict__ w_atr) {
    __shared__ float s_sums[256];
    __shared__ float s_dot[256];
    int n = blockIdx.x, t = threadIdx.x;
    const float* pp = partials + (size_t)n * 144 * 256 + t;
    float s = 0.f;
#pragma unroll 8
    for (int k = 0; k < 144; ++k) s += pp[k * 256];
    s_sums[t] = s * (1.0f / (float)HW);
    __syncthreads();
    int cm = t & 63, seg = t >> 6;
    const uint16_t* wr = cw_bf + cm * 256 + seg * 64;
    const float* sr = s_sums + seg * 64;
    float acc = 0.f;
#pragma unroll 8
    for (int c = 0; c < 64; ++c) acc = fmaf(ldbf(wr + c), sr[c], acc);
    s_dot[t] = acc;
    __syncthreads();
    if (t < 64) {
        float a = s_dot[t] + s_dot[t + 64] + s_dot[t + 128] + s_dot[t + 192]
                + smalls[CB_OFF + t];
        float gv = fmaxf(a, 0.f);
        float ckw = smalls[SC_OFF + 0], ckb = smalls[SC_OFF + 1];
        float ck2w = smalls[SC_OFF + 2], ck2b = smalls[SC_OFF + 3];
        float* o1 = w_dyn + (size_t)(n * CMID + t) * 25;
#pragma unroll
        for (int k = 0; k < 25; ++k)
            o1[k] = fmaf(ckw, fmaf(gv, smalls[KW_OFF + k], smalls[KB_OFF + k]), ckb);
        float* o2 = w_atr + (size_t)(n * CMID + t) * 9;
#pragma unroll
        for (int k = 0; k < 9; ++k)
            o2[k] = fmaf(ck2w, fmaf(gv, smalls[K2W_OFF + k], smalls[K2B_OFF + k]), ck2b);
    }
}

// ---------- K3: dynamic depthwise (5x5 + atrous 3x3) + MFMA fuse GEMM ----------
// Row-streamed depthwise + LDS union (20480 B). __launch_bounds__(256,4):
// VGPR budget 128 >> ~90 live regs -> NO spill (the (256,5) cap in the prior
// round spilled ~108 MB to scratch). 4 blocks/CU.
__global__ __launch_bounds__(256, 4) void k_dwfuse(
    const uint16_t* __restrict__ f,
    const float* __restrict__ w_dyn, const float* __restrict__ w_atr,
    const uint16_t* __restrict__ fw_bf, const float* __restrict__ smalls,
    float* __restrict__ out) {
    __shared__ uint16_t u_lds[160 * 64];      // 20480 B: f halo, then d5|dA union
    uint16_t* d5_lds = u_lds;                 // [px 4x16][c] pad 72: 9216 B
    uint16_t* dA_lds = u_lds + 64 * 72;       // 9216 B (total 18432 <= 20480)

    int t = threadIdx.x;
    int orig = blockIdx.x;
    int b = (orig & 7) * 288 + (orig >> 3);   // XCD swizzle (2304 % 8 == 0, bijective)
    int n = b / 144, tile = b % 144;
    int y0 = (tile / 6) * 4, x0 = (tile % 6) * 16;

    // stage f halo 8 rows x 20 cols x 64c FIRST (HBM/L2 latency starts earliest)
    const uint16_t* fbase = f + (size_t)n * HW * 64;
#pragma unroll
    for (int k = 0; k < 5; ++k) {
        int task = k * 256 + t;
        int row = task >> 3, c8 = (task & 7) * 8;
        int hy = row / 20, hx = row - hy * 20;
        int y = y0 - 2 + hy, xg = x0 - 2 + hx;
        uint4 v = make_uint4(0u, 0u, 0u, 0u);
        if (y >= 0 && y < HH && xg >= 0 && xg < WW)
            v = *(const uint4*)(fbase + ((size_t)y * WW + xg) * 64 + c8);
        *(uint4*)(u_lds + row * 64 + (c8 ^ SWZ8(row))) = v;
    }

    // per-channel dynamic weights (small, L2-resident)
    int c = t >> 2, q = t & 3;
    int qx = q << 2;
    float w5[25], w9[9];
    {
        const float* wp = w_dyn + (size_t)(n * CMID + c) * 25;
#pragma unroll
        for (int k = 0; k < 25; ++k) w5[k] = wp[k];
        const float* wa = w_atr + (size_t)(n * CMID + c) * 9;
#pragma unroll
        for (int k = 0; k < 9; ++k) w9[k] = wa[k];
    }
    __syncthreads();

    // ---- row-streamed depthwise: 1 channel x 4x4 outputs per thread ----
    float b5v = smalls[AB_OFF + c], bAv = smalls[ATB_OFF + c];
    float a5[4][4], aA[4][4];
#pragma unroll
    for (int i = 0; i < 4; ++i)
#pragma unroll
        for (int j = 0; j < 4; ++j) { a5[i][j] = b5v; aA[i][j] = bAv; }

#pragma unroll
    for (int r = 0; r < 8; ++r) {
        float row[8];
#pragma unroll
        for (int cl = 0; cl < 8; ++cl) {
            int rw = r * 20 + qx + cl;
            row[cl] = ldbf(u_lds + rw * 64 + (c ^ SWZ8(rw)));
        }
#pragma unroll
        for (int oy = 0; oy < 4; ++oy) {
            int d = r - oy;
            if (d >= 0 && d <= 4) {
#pragma unroll
                for (int j = 0; j < 5; ++j) {
                    float wv = w5[d * 5 + j];
#pragma unroll
                    for (int ox = 0; ox < 4; ++ox)
                        a5[oy][ox] = fmaf(wv, row[ox + j], a5[oy][ox]);
                }
            }
            if (d >= 0 && d <= 4 && (d & 1) == 0) {
                int i2 = d >> 1;
#pragma unroll
                for (int j = 0; j < 3; ++j) {
                    float wv = w9[i2 * 3 + j];
#pragma unroll
                    for (int ox = 0; ox < 4; ++ox)
                        aA[oy][ox] = fmaf(wv, row[ox + 2 * j], aA[oy][ox]);
                }
            }
        }
    }
    __syncthreads();                          // all f reads done; union now writable

#pragma unroll
    for (int oy = 0; oy < 4; ++oy)
#pragma unroll
        for (int ox = 0; ox < 4; ox += 2) {
            int pxo = oy * 16 + qx + ox;
            uint32_t p5 = pkbf(a5[oy][ox], a5[oy][ox + 1]);
            uint32_t pA = pkbf(aA[oy][ox], aA[oy][ox + 1]);
            d5_lds[pxo * 72 + c]       = (uint16_t)p5;
            d5_lds[(pxo + 1) * 72 + c] = (uint16_t)(p5 >> 16);
            dA_lds[pxo * 72 + c]       = (uint16_t)pA;
            dA_lds[(pxo + 1) * 72 + c] = (uint16_t)(pA >> 16);
        }
    __syncthreads();

    // ---- fuse GEMM: A = d[px][c] (LDS), B = fw^T (global/L2) ----
    {
        int lane = t & 63, wid = t >> 6;
        int l16 = lane & 15, quad = lane >> 4;
        const uint16_t* dl = (wid >= 2) ? dA_lds : d5_lds;
        int oh = (wid & 1) * 64;
        int obr = (wid >= 2) ? 128 : 0;

        floatx4 acc[4][4];                    // [mt=px group][nt=o group]
#pragma unroll
        for (int i = 0; i < 4; ++i)
#pragma unroll
            for (int j = 0; j < 4; ++j) acc[i][j] = (floatx4){0.f, 0.f, 0.f, 0.f};

#pragma unroll
        for (int ks = 0; ks < 2; ++ks) {
            int kk = ks * 32 + quad * 8;
            short8 a0 = *(const short8*)(dl + (l16)      * 72 + kk);
            short8 a1 = *(const short8*)(dl + (16 + l16) * 72 + kk);
            short8 a2 = *(const short8*)(dl + (32 + l16) * 72 + kk);
            short8 a3 = *(const short8*)(dl + (48 + l16) * 72 + kk);
#pragma unroll
            for (int nt = 0; nt < 4; ++nt) {
                short8 bv = *(const short8*)(fw_bf + (size_t)(oh + nt * 16 + l16) * 64 + kk);
                acc[0][nt] = __builtin_amdgcn_mfma_f32_16x16x32_bf16(a0, bv, acc[0][nt], 0, 0, 0);
                acc[1][nt] = __builtin_amdgcn_mfma_f32_16x16x32_bf16(a1, bv, acc[1][nt], 0, 0, 0);
                acc[2][nt] = __builtin_amdgcn_mfma_f32_16x16x32_bf16(a2, bv, acc[2][nt], 0, 0, 0);
                acc[3][nt] = __builtin_amdgcn_mfma_f32_16x16x32_bf16(a3, bv, acc[3][nt], 0, 0, 0);
            }
        }
        // store: px = mt*16 + quad*4 + reg -> y = y0+mt, x = x0 + quad*4 + reg
#pragma unroll
        for (int nt = 0; nt < 4; ++nt) {
            int o = oh + nt * 16 + l16;
            float bias = smalls[FB_OFF + o];
            float* obp = out + ((size_t)(n * 256 + obr + o)) * HW + x0 + quad * 4;
#pragma unroll
            for (int mt = 0; mt < 4; ++mt) {
                float4 v;
                v.x = acc[mt][nt][0] + bias;
                v.y = acc[mt][nt][1] + bias;
                v.z = acc[mt][nt][2] + bias;
                v.w = acc[mt][nt][3] + bias;
                *(float4*)(obp + (size_t)(y0 + mt) * WW) = v;
            }
        }
    }
}

extern "C" void kernel_launch(void* const* d_in, const int* in_sizes, int n_in,
                              void* d_out, int out_size, void* d_ws, size_t ws_size,
                              hipStream_t stream) {
    float* out = (float*)d_out;                              // fp32 output

    char* ws = (char*)d_ws;
    int*      flags = (int*)ws;                              // 256 B
    uint16_t* cw_bf = (uint16_t*)(ws + 256);                 // 32768 B [o][c]
    uint16_t* fw_bf = (uint16_t*)(ws + 33024);               // 16384 B [o][c]
    float*    smalls = (float*)(ws + 49408);                 // 2048 B
    float*    partials = (float*)(ws + 65536);               // 2359296 B [n][144][256]
    float*    w_dyn = (float*)(ws + 2424832);                // 102400 B
    float*    w_atr = (float*)(ws + 2527232);                // 36864 B
    uint16_t* f     = (uint16_t*)(ws + 2564096);             // 18.9 MB [n][px][c] bf16

    k_prep<<<dim3(16), dim3(256), 0, stream>>>(
        (const uint16_t*)d_in[0],
        d_in[1], d_in[2], d_in[3], d_in[4], d_in[5], d_in[6], d_in[7], d_in[8],
        d_in[9], d_in[10], d_in[11], d_in[12], d_in[13], d_in[14],
        flags, cw_bf, fw_bf, smalls);
    k_conv1x1<<<dim3(N_S * 144), dim3(256), 0, stream>>>(
        d_in[0], flags, cw_bf, smalls, f, partials);
    k_weights2<<<dim3(N_S), dim3(256), 0, stream>>>(
        partials, cw_bf, smalls, w_dyn, w_atr);
    k_dwfuse<<<dim3(N_S * 144), dim3(256), 0, stream>>>(
        f, w_dyn, w_atr, fw_bf, smalls, out);
}